// Round 12
// baseline (251.835 us; speedup 1.0000x reference)
//
#include <hip/hip_runtime.h>
#include <hip/hip_bf16.h>

#define GRID_W 64
#define NPTS   4096
#define BATCH  8
#define DD     32
#define DIN    80
#define HID    128
#define SH_STRIDE 136              // ushort stride (17*16B) -> conflict-free b128
#define SQ_STRIDE 36               // f32 stride for LDS state rows
#define NBLK   512                 // one grid-row per block
#define NSTEP  34                  // max half-steps for tf <= 4.0
// ws layout: per-WAVE flags (512 blk * 4 waves * 64B = 128 KB) | fragments | ebuf
#define OFF_F1Q 131072
#define OFF_F2Q (OFF_F1Q + 24*64*16)
#define OFF_F1P (OFF_F2Q + 8*64*16)
#define OFF_F2P (OFF_F1P + 24*64*16)
#define OFF_EBUF 262144
// ebuf: [b][row][pt][q(32)|p(32)] bf16 = 8*64*64*64*2 = 4 MB

typedef __attribute__((ext_vector_type(8))) short short8;
typedef __attribute__((ext_vector_type(4))) float f32x4;
typedef unsigned long long u64;

__device__ __forceinline__ ushort f2bf(float v) {
    __hip_bfloat16 h = __float2bfloat16(v);
    return __builtin_bit_cast(ushort, h);
}
__device__ __forceinline__ uint packbf(float a, float b) {
    return (uint)f2bf(a) | ((uint)f2bf(b) << 16);
}
__device__ __forceinline__ short8 pack8(float4 a, float4 b) {
    union { uint u[4]; short8 s; } t;
    t.u[0] = packbf(a.x, a.y); t.u[1] = packbf(a.z, a.w);
    t.u[2] = packbf(b.x, b.y); t.u[3] = packbf(b.z, b.w);
    return t.s;
}
__device__ __forceinline__ float bf2f(ushort u) {
    union { uint i; float f; } t; t.i = ((uint)u) << 16; return t.f;
}

// System-scope (coherence-point) accessors. Proven rounds 5-11.
__device__ __forceinline__ short8 ld_sysh8(const ushort* p) {   // 16B = 8 bf16
    union { u64 v[2]; short8 s; } t;
    t.v[0] = __hip_atomic_load((const u64*)p,       __ATOMIC_RELAXED, __HIP_MEMORY_SCOPE_SYSTEM);
    t.v[1] = __hip_atomic_load((const u64*)(p + 4), __ATOMIC_RELAXED, __HIP_MEMORY_SCOPE_SYSTEM);
    return t.s;
}
__device__ __forceinline__ void st_sysb4(ushort* p, float4 v) { // 8B = 4 bf16
    u64 pk = (u64)packbf(v.x, v.y) | ((u64)packbf(v.z, v.w) << 32);
    __hip_atomic_store((u64*)p, pk, __ATOMIC_RELAXED, __HIP_MEMORY_SCOPE_SYSTEM);
}

// Pack W1/W2 (both sets) into MFMA B-fragment order in ws (unchanged r4-r11).
__global__ void pack_weights(const float* __restrict__ W1q, const float* __restrict__ W2q,
                             const float* __restrict__ W1p, const float* __restrict__ W2p,
                             char* __restrict__ ws)
{
    const int s = blockIdx.x;
    const float* W1 = s ? W1p : W1q;
    const float* W2 = s ? W2p : W2q;
    ushort* f1 = (ushort*)(ws + (s ? OFF_F1P : OFF_F1Q));
    ushort* f2 = (ushort*)(ws + (s ? OFF_F2P : OFF_F2Q));
    for (int idx = threadIdx.x; idx < 24 * 512; idx += 256) {
        int f = idx >> 9, rem = idx & 511, lane = rem >> 3, j = rem & 7;
        int ks = f >> 3, nt = f & 7;
        int k = ks * 32 + (lane >> 4) * 8 + j, n = nt * 16 + (lane & 15);
        f1[idx] = f2bf(k < DIN ? W1[k * HID + n] : 0.0f);
    }
    for (int idx = threadIdx.x; idx < 8 * 512; idx += 256) {
        int f = idx >> 9, rem = idx & 511, lane = rem >> 3, j = rem & 7;
        int ks = f >> 1, nt = f & 1;
        int k = ks * 32 + (lane >> 4) * 8 + j, n = nt * 16 + (lane & 15);
        f2[idx] = f2bf(W2[k * DD + n]);
    }
}

// Initial q/p -> bf16 exchange buffer.
__global__ void init_ebuf(const float* __restrict__ x, char* __restrict__ ws)
{
    const int blk = blockIdx.x, tid = threadIdx.x;
    const int b = blk >> 6, r = blk & 63;
    const int pt = tid >> 2, sg = (tid & 3) * 8;
    const float* src = x + (size_t)(b * NPTS + r * GRID_W + pt) * DIN;
    ushort* drow = (ushort*)(ws + OFF_EBUF) + ((size_t)(b * 64 + r) * 64 + pt) * 64;
    float4 q0 = *(const float4*)(src + sg),      q1 = *(const float4*)(src + sg + 4);
    float4 p0 = *(const float4*)(src + DD + sg), p1 = *(const float4*)(src + DD + sg + 4);
    *(uint*)&drow[sg]          = packbf(q0.x, q0.y);
    *(uint*)&drow[sg + 2]      = packbf(q0.z, q0.w);
    *(uint*)&drow[sg + 4]      = packbf(q1.x, q1.y);
    *(uint*)&drow[sg + 6]      = packbf(q1.z, q1.w);
    *(uint*)&drow[32 + sg]     = packbf(p0.x, p0.y);
    *(uint*)&drow[32 + sg + 2] = packbf(p0.z, p0.w);
    *(uint*)&drow[32 + sg + 4] = packbf(p1.x, p1.y);
    *(uint*)&drow[32 + sg + 6] = packbf(p1.z, p1.w);
}

struct Acc2 { f32x4 a0, a1; };

// (fallback-only) full F-eval helper
__device__ __forceinline__ Acc2 eval_F(short8 af0, short8 af1, short8 af2,
    const short8* __restrict__ F1, const short8* __restrict__ w2,
    const float* __restrict__ B1, ushort* __restrict__ sH,
    int wv, int lane, int l16, int quad, int q8)
{
    f32x4 acc1[8];
    #pragma unroll
    for (int nt = 0; nt < 8; ++nt) acc1[nt] = (f32x4){0.f, 0.f, 0.f, 0.f};
    #pragma unroll
    for (int nt = 0; nt < 8; ++nt)
        acc1[nt] = __builtin_amdgcn_mfma_f32_16x16x32_bf16(af0, F1[nt * 64 + lane], acc1[nt], 0, 0, 0);
    #pragma unroll
    for (int nt = 0; nt < 8; ++nt)
        acc1[nt] = __builtin_amdgcn_mfma_f32_16x16x32_bf16(af1, F1[(8 + nt) * 64 + lane], acc1[nt], 0, 0, 0);
    #pragma unroll
    for (int nt = 0; nt < 8; ++nt)
        acc1[nt] = __builtin_amdgcn_mfma_f32_16x16x32_bf16(af2, F1[(16 + nt) * 64 + lane], acc1[nt], 0, 0, 0);
    #pragma unroll
    for (int nt = 0; nt < 8; ++nt) {
        const int col = nt * 16 + l16;
        const float bias = B1[col];
        #pragma unroll
        for (int rg = 0; rg < 4; ++rg) {
            const int rowm = wv * 16 + quad * 4 + rg;
            float s = acc1[nt][rg] + bias;
            float e = __expf(2.0f * s);
            float hh = 1.0f - __fdividef(2.0f, e + 1.0f);
            sH[rowm * SH_STRIDE + col] = f2bf(hh);
        }
    }
    Acc2 o;
    o.a0 = (f32x4){0.f, 0.f, 0.f, 0.f};
    o.a1 = (f32x4){0.f, 0.f, 0.f, 0.f};
    #pragma unroll
    for (int ks = 0; ks < 4; ++ks) {
        short8 af = *(const short8*)&sH[(wv * 16 + l16) * SH_STRIDE + ks * 32 + q8];
        o.a0 = __builtin_amdgcn_mfma_f32_16x16x32_bf16(af, w2[ks * 2 + 0], o.a0, 0, 0, 0);
        o.a1 = __builtin_amdgcn_mfma_f32_16x16x32_bf16(af, w2[ks * 2 + 1], o.a1, 0, 0, 0);
    }
    return o;
}

// Wave-autonomous rings (r11) + bias-in-registers + early-L3-flag epilogue.
__global__ __launch_bounds__(256, 2) void sympl_coop(
    float* __restrict__ out, const float* __restrict__ tfinal,
    char* __restrict__ ws,
    const float* __restrict__ b1q, const float* __restrict__ b2q,
    const float* __restrict__ b1p, const float* __restrict__ b2p)
{
    __shared__ __align__(16) float  sQ[64 * SQ_STRIDE];
    __shared__ __align__(16) float  sP[64 * SQ_STRIDE];
    __shared__ __align__(16) ushort sH[64 * SH_STRIDE];
    __shared__ __align__(16) float  sO[4 * 512];
    __shared__ uint ldsF[4];

    uint* flags = (uint*)ws;
    ushort* ebuf = (ushort*)(ws + OFF_EBUF);
    const int blk = blockIdx.x, tid = threadIdx.x;
    const int b = blk >> 6, r = blk & 63;
    const int wv = tid >> 6, lane = tid & 63;
    const int l16 = lane & 15, quad = lane >> 4, q8 = quad * 8;
    const int c = wv * 16 + l16;
    const int rm = (r + 63) & 63, rp = (r + 1) & 63;
    const int cm = (c + 63) & 63, cp = (c + 1) & 63;
    const int pt = tid >> 2, sg = (tid & 3) * 8;

    uint* flLw = flags + (((size_t)(b * 64 + rm) * 4) + wv) * 16;
    uint* flRw = flags + (((size_t)(b * 64 + rp) * 4) + wv) * 16;
    uint* flOw = flags + (((size_t)(b * 64 + r ) * 4) + wv) * 16;

    // ---- init: own-row q/p -> LDS fp32; xi, W2 frags, biases -> registers ----
    {
        const float* src = out + (size_t)(b * NPTS + r * GRID_W + pt) * DIN;
        *(float4*)&sQ[pt * SQ_STRIDE + sg]     = *(const float4*)(src + sg);
        *(float4*)&sQ[pt * SQ_STRIDE + sg + 4] = *(const float4*)(src + sg + 4);
        *(float4*)&sP[pt * SQ_STRIDE + sg]     = *(const float4*)(src + DD + sg);
        *(float4*)&sP[pt * SQ_STRIDE + sg + 4] = *(const float4*)(src + DD + sg + 4);
    }
    if (tid < 4) ldsF[tid] = 0;
    short8 af2;
    if (quad < 2) {
        const float* px = out + (size_t)(b * NPTS + r * GRID_W + c) * DIN + 2 * DD + q8;
        af2 = pack8(*(const float4*)px, *(const float4*)(px + 4));
    } else {
        af2 = (short8)(short)0;
    }
    short8 w2q[8], w2p[8];
    {
        const short8* F2q = (const short8*)(ws + OFF_F2Q);
        const short8* F2p = (const short8*)(ws + OFF_F2P);
        #pragma unroll
        for (int i = 0; i < 8; ++i) { w2q[i] = F2q[i * 64 + lane]; w2p[i] = F2p[i * 64 + lane]; }
    }
    float b1rq[8], b1rp[8], b2rq[2], b2rp[2];
    #pragma unroll
    for (int nt = 0; nt < 8; ++nt) {
        b1rq[nt] = b1q[nt * 16 + l16];
        b1rp[nt] = b1p[nt * 16 + l16];
    }
    #pragma unroll
    for (int nt = 0; nt < 2; ++nt) {
        b2rq[nt] = b2q[nt * 16 + l16];
        b2rp[nt] = b2p[nt * 16 + l16];
    }
    const float tf = tfinal[b];
    __syncthreads();                        // LDS state + ldsF visible

    const ushort* e_rm = ebuf + ((size_t)(b * 64 + rm) * 64 + c) * 64;
    const ushort* e_rp = ebuf + ((size_t)(b * 64 + rp) * 64 + c) * 64;
    const int wl = (wv + 3) & 3, wr = (wv + 1) & 3;

    float tq = 0.0f, tp = 0.0f;
    #pragma unroll 1
    for (int h = 0; h < NSTEP; ++h) {
        const int phase = h & 1;            // 0: q += dt*F(p); 1: p += dt*F(q)
        const float dtmax = phase ? 0.25f : ((h == 0) ? 0.125f : 0.25f);
        const float tcur  = phase ? tp : tq;
        if (!phase && tq >= tf) break;      // batch-uniform: all rings exit together
        if (h > 0) {                        // wave-level lag-1 wait (hot spin)
            const uint tgt = (uint)h;
            while (true) {
                uint v = tgt;
                if (lane == 0)      v = __hip_atomic_load(flLw, __ATOMIC_RELAXED, __HIP_MEMORY_SCOPE_SYSTEM);
                else if (lane == 1) v = __hip_atomic_load(flRw, __ATOMIC_RELAXED, __HIP_MEMORY_SCOPE_SYSTEM);
                else if (lane == 2) v = __hip_atomic_load(&ldsF[wl], __ATOMIC_RELAXED, __HIP_MEMORY_SCOPE_WORKGROUP);
                else if (lane == 3) v = __hip_atomic_load(&ldsF[wr], __ATOMIC_RELAXED, __HIP_MEMORY_SCOPE_WORKGROUP);
                if (__all((int)(v >= tgt))) break;
            }
        }

        const float dt = fminf(fmaxf(tf - tcur, 0.0f), dtmax);
        float4 oo0, oo1;
        float *pl0 = nullptr, *pl1 = nullptr;
        const bool act = (dt > 0.0f);       // block-uniform
        if (act) {
            const int so  = phase ? 0 : 32;     // src half in ebuf (q:0, p:32)
            const int dso = phase ? 32 : 0;     // dst half
            const float* srcL = phase ? sQ : sP;
            float*       dstL = phase ? sP : sQ;

            // neighbor rows (bf16, sys; issue FIRST, consumed LAST)
            short8 upv = ld_sysh8(e_rm + so + q8);
            short8 dnv = ld_sysh8(e_rp + so + q8);

            // self from LDS -> af0; run af0+af2 MFMAs while loads fly
            const float* s0p = srcL + c * SQ_STRIDE + q8;
            float4 a0 = *(const float4*)s0p, a1 = *(const float4*)(s0p + 4);
            short8 af0 = pack8(a0, a1);

            const short8* F1 = (const short8*)(ws + (phase ? OFF_F1P : OFF_F1Q));
            f32x4 acc1[8];
            #pragma unroll
            for (int nt = 0; nt < 8; ++nt) acc1[nt] = (f32x4){0.f, 0.f, 0.f, 0.f};
            #pragma unroll
            for (int nt = 0; nt < 8; ++nt)
                acc1[nt] = __builtin_amdgcn_mfma_f32_16x16x32_bf16(af0, F1[nt * 64 + lane], acc1[nt], 0, 0, 0);
            #pragma unroll
            for (int nt = 0; nt < 8; ++nt)
                acc1[nt] = __builtin_amdgcn_mfma_f32_16x16x32_bf16(af2, F1[(16 + nt) * 64 + lane], acc1[nt], 0, 0, 0);

            // column neighbors (LDS) + row neighbors (loads) -> af1, last
            const float* smp = srcL + cm * SQ_STRIDE + q8;
            const float* spp = srcL + cp * SQ_STRIDE + q8;
            float4 lf0 = *(const float4*)smp, lf1 = *(const float4*)(smp + 4);
            float4 rt0 = *(const float4*)spp, rt1 = *(const float4*)(spp + 4);
            float4 m0, m1;
            m0.x = 0.25f * (bf2f((ushort)upv[0]) + bf2f((ushort)dnv[0]) + lf0.x + rt0.x);
            m0.y = 0.25f * (bf2f((ushort)upv[1]) + bf2f((ushort)dnv[1]) + lf0.y + rt0.y);
            m0.z = 0.25f * (bf2f((ushort)upv[2]) + bf2f((ushort)dnv[2]) + lf0.z + rt0.z);
            m0.w = 0.25f * (bf2f((ushort)upv[3]) + bf2f((ushort)dnv[3]) + lf0.w + rt0.w);
            m1.x = 0.25f * (bf2f((ushort)upv[4]) + bf2f((ushort)dnv[4]) + lf1.x + rt1.x);
            m1.y = 0.25f * (bf2f((ushort)upv[5]) + bf2f((ushort)dnv[5]) + lf1.y + rt1.y);
            m1.z = 0.25f * (bf2f((ushort)upv[6]) + bf2f((ushort)dnv[6]) + lf1.z + rt1.z);
            m1.w = 0.25f * (bf2f((ushort)upv[7]) + bf2f((ushort)dnv[7]) + lf1.w + rt1.w);
            short8 af1 = pack8(m0, m1);
            #pragma unroll
            for (int nt = 0; nt < 8; ++nt)
                acc1[nt] = __builtin_amdgcn_mfma_f32_16x16x32_bf16(af1, F1[(8 + nt) * 64 + lane], acc1[nt], 0, 0, 0);

            // tanh -> sH (wave-local rows); biases from registers
            #pragma unroll
            for (int nt = 0; nt < 8; ++nt) {
                const int col = nt * 16 + l16;
                const float bias = phase ? b1rp[nt] : b1rq[nt];
                #pragma unroll
                for (int rg = 0; rg < 4; ++rg) {
                    const int rowm = wv * 16 + quad * 4 + rg;
                    float s = acc1[nt][rg] + bias;
                    float e = __expf(2.0f * s);
                    float hh = 1.0f - __fdividef(2.0f, e + 1.0f);
                    sH[rowm * SH_STRIDE + col] = f2bf(hh);
                }
            }
            // GEMM2 (register-resident W2)
            const short8* w2 = phase ? w2p : w2q;
            f32x4 o0 = (f32x4){0.f, 0.f, 0.f, 0.f};
            f32x4 o1 = (f32x4){0.f, 0.f, 0.f, 0.f};
            #pragma unroll
            for (int ks = 0; ks < 4; ++ks) {
                short8 af = *(const short8*)&sH[(wv * 16 + l16) * SH_STRIDE + ks * 32 + q8];
                o0 = __builtin_amdgcn_mfma_f32_16x16x32_bf16(af, w2[ks * 2 + 0], o0, 0, 0, 0);
                o1 = __builtin_amdgcn_mfma_f32_16x16x32_bf16(af, w2[ks * 2 + 1], o1, 0, 0, 0);
            }
            // O -> wave-private sO
            float* sOw = sO + wv * 512;
            #pragma unroll
            for (int nt = 0; nt < 2; ++nt) {
                const int col = nt * 16 + l16;
                const float b2v = phase ? b2rp[nt] : b2rq[nt];
                const f32x4 av = nt ? o1 : o0;
                #pragma unroll
                for (int rg = 0; rg < 4; ++rg)
                    sOw[(quad * 4 + rg) * DD + col] = av[rg] + b2v;
            }
            // compute both RMW results, issue ALL sys-stores first
            {
                const int lr0 = lane >> 3, seg0 = (lane & 7) * 4;
                const int pt0 = wv * 16 + lr0;
                const float* po0 = &sOw[lr0 * DD + seg0];
                pl0 = dstL + pt0 * SQ_STRIDE + seg0;
                float4 o = *(const float4*)pl0;
                o.x += dt * po0[0]; o.y += dt * po0[1];
                o.z += dt * po0[2]; o.w += dt * po0[3];
                oo0 = o;
                st_sysb4(ebuf + ((size_t)(b * 64 + r) * 64 + pt0) * 64 + dso + seg0, o);

                const int slot = lane + 64;
                const int lr1 = slot >> 3, seg1 = (slot & 7) * 4;
                const int pt1 = wv * 16 + lr1;
                const float* po1 = &sOw[lr1 * DD + seg1];
                pl1 = dstL + pt1 * SQ_STRIDE + seg1;
                float4 o2 = *(const float4*)pl1;
                o2.x += dt * po1[0]; o2.y += dt * po1[1];
                o2.z += dt * po1[2]; o2.w += dt * po1[3];
                oo1 = o2;
                st_sysb4(ebuf + ((size_t)(b * 64 + r) * 64 + pt1) * 64 + dso + seg1, o2);
            }
        }
        // early L3 flag: only guards ebuf (sys stores drained). LDS writes after.
        __asm__ volatile("s_waitcnt vmcnt(0)" ::: "memory");
        if (lane == 0)
            __hip_atomic_store(flOw, (uint)(h + 1), __ATOMIC_RELAXED, __HIP_MEMORY_SCOPE_SYSTEM);
        if (act) {
            *(float4*)pl0 = oo0;
            *(float4*)pl1 = oo1;
        }
        __asm__ volatile("s_waitcnt lgkmcnt(0)" ::: "memory");
        if (lane == 0)
            __hip_atomic_store(&ldsF[wv], (uint)(h + 1), __ATOMIC_RELAXED, __HIP_MEMORY_SCOPE_WORKGROUP);
        if (phase) tp += dtmax; else tq += dtmax;
    }

    // ---- final state -> d_out (pt rows are wave-private: no barrier) ----
    {
        float* dst = out + (size_t)(b * NPTS + r * GRID_W + pt) * DIN;
        *(float4*)(dst + sg)          = *(const float4*)&sQ[pt * SQ_STRIDE + sg];
        *(float4*)(dst + sg + 4)      = *(const float4*)&sQ[pt * SQ_STRIDE + sg + 4];
        *(float4*)(dst + DD + sg)     = *(const float4*)&sP[pt * SQ_STRIDE + sg];
        *(float4*)(dst + DD + sg + 4) = *(const float4*)&sP[pt * SQ_STRIDE + sg + 4];
    }
}

// ---------------- fallback path (round-8-proven, global fp32 state) ----------------
__global__ __launch_bounds__(256, 2) void sympl_step(
    float* __restrict__ state, const float* __restrict__ tfinal,
    const char* __restrict__ ws,
    const float* __restrict__ B1, const float* __restrict__ B2,
    int phase, float tcur, float dtmax)
{
    __shared__ __align__(16) ushort sH[64 * SH_STRIDE];
    __shared__ __align__(16) float  sO[4 * 512];
    const int blk = blockIdx.x, tid = threadIdx.x;
    const int wv = tid >> 6, lane = tid & 63;
    const int l16 = lane & 15, quad = lane >> 4, q8 = quad * 8;
    const int b = blk >> 6, r = blk & 63;
    const int c = wv * 16 + l16;

    const float tf = tfinal[b];
    const float dt = fminf(fmaxf(tf - tcur, 0.0f), dtmax);
    if (dt <= 0.0f) return;

    const int srcoff = phase ? 0 : DD;
    const int dstoff = phase ? DD : 0;
    float* bb = state + (size_t)b * NPTS * DIN;
    const float* selfp = bb + (r * GRID_W + c) * DIN;
    const int rm = (r + 63) & 63, rp = (r + 1) & 63;
    const int cm = (c + 63) & 63, cp = (c + 1) & 63;
    short8 af0, af1, af2;
    {
        const float* ps = selfp + srcoff + q8;
        af0 = pack8(*(const float4*)ps, *(const float4*)(ps + 4));
    }
    {
        const float* p0 = bb + (rm * GRID_W + c) * DIN + srcoff + q8;
        const float* p1 = bb + (rp * GRID_W + c) * DIN + srcoff + q8;
        const float* p2 = bb + (r * GRID_W + cm) * DIN + srcoff + q8;
        const float* p3 = bb + (r * GRID_W + cp) * DIN + srcoff + q8;
        float4 a0 = *(const float4*)p0, a1 = *(const float4*)(p0 + 4);
        float4 b0 = *(const float4*)p1, b1v = *(const float4*)(p1 + 4);
        float4 c0 = *(const float4*)p2, c1 = *(const float4*)(p2 + 4);
        float4 d0 = *(const float4*)p3, d1 = *(const float4*)(p3 + 4);
        float4 m0, m1;
        m0.x = 0.25f * (a0.x + b0.x + c0.x + d0.x);
        m0.y = 0.25f * (a0.y + b0.y + c0.y + d0.y);
        m0.z = 0.25f * (a0.z + b0.z + c0.z + d0.z);
        m0.w = 0.25f * (a0.w + b0.w + c0.w + d0.w);
        m1.x = 0.25f * (a1.x + b1v.x + c1.x + d1.x);
        m1.y = 0.25f * (a1.y + b1v.y + c1.y + d1.y);
        m1.z = 0.25f * (a1.z + b1v.z + c1.z + d1.z);
        m1.w = 0.25f * (a1.w + b1v.w + c1.w + d1.w);
        af1 = pack8(m0, m1);
    }
    if (quad < 2) {
        const float* px = selfp + 2 * DD + q8;
        af2 = pack8(*(const float4*)px, *(const float4*)(px + 4));
    } else {
        af2 = (short8)(short)0;
    }
    const short8* F1 = (const short8*)(ws + (phase ? OFF_F1P : OFF_F1Q));
    const short8* F2 = (const short8*)(ws + (phase ? OFF_F2P : OFF_F2Q));
    short8 w2[8];
    #pragma unroll
    for (int i = 0; i < 8; ++i) w2[i] = F2[i * 64 + lane];
    Acc2 A = eval_F(af0, af1, af2, F1, w2, B1, sH, wv, lane, l16, quad, q8);
    float* sOw = sO + wv * 512;
    #pragma unroll
    for (int nt = 0; nt < 2; ++nt) {
        const int col = nt * 16 + l16;
        const float b2v = B2[col];
        const f32x4 av = nt ? A.a1 : A.a0;
        #pragma unroll
        for (int rg = 0; rg < 4; ++rg)
            sOw[(quad * 4 + rg) * DD + col] = av[rg] + b2v;
    }
    #pragma unroll
    for (int it = 0; it < 2; ++it) {
        const int slot = lane + it * 64;
        const int lr = slot >> 3, seg = (slot & 7) * 4;
        float* pd = bb + (r * GRID_W + wv * 16 + lr) * DIN + dstoff + seg;
        const float* po = &sOw[lr * DD + seg];
        float4 o = *(const float4*)pd;
        o.x += dt * po[0]; o.y += dt * po[1];
        o.z += dt * po[2]; o.w += dt * po[3];
        *(float4*)pd = o;
    }
}

extern "C" void kernel_launch(void* const* d_in, const int* in_sizes, int n_in,
                              void* d_out, int out_size, void* d_ws, size_t ws_size,
                              hipStream_t stream)
{
    const float* x   = (const float*)d_in[0];
    const float* tf  = (const float*)d_in[1];
    const float* W1q = (const float*)d_in[2];
    const float* b1q = (const float*)d_in[3];
    const float* W2q = (const float*)d_in[4];
    const float* b2q = (const float*)d_in[5];
    const float* W1p = (const float*)d_in[6];
    const float* b1p = (const float*)d_in[7];
    const float* W2p = (const float*)d_in[8];
    const float* b2p = (const float*)d_in[9];
    float* out = (float*)d_out;
    char* ws = (char*)d_ws;

    // d_out: [b][i][q(32) p(32) xi(16)] — xi + initial state
    hipMemcpyAsync(out, x, (size_t)BATCH * NPTS * DIN * sizeof(float),
                   hipMemcpyDeviceToDevice, stream);
    hipMemsetAsync(ws, 0, NBLK * 4 * 64, stream);      // per-wave step flags
    pack_weights<<<dim3(2), dim3(256), 0, stream>>>(W1q, W2q, W1p, W2p, ws);
    init_ebuf<<<dim3(NBLK), dim3(256), 0, stream>>>(x, ws);

    void* args[] = { (void*)&out, (void*)&tf, (void*)&ws,
                     (void*)&b1q, (void*)&b2q, (void*)&b1p, (void*)&b2p };
    hipError_t e = hipLaunchCooperativeKernel((const void*)sympl_coop,
                                              dim3(NBLK), dim3(256), args, 0, stream);
    if (e != hipSuccess) {
        // Fallback: 34 regular launches (kernel-boundary coherence).
        float tq = 0.0f, tp = 0.0f;
        for (int h = 0; h < NSTEP; ++h) {
            const int phase = h & 1;
            const float dtmax = phase ? 0.25f : ((h == 0) ? 0.125f : 0.25f);
            const float tcur  = phase ? tp : tq;
            sympl_step<<<dim3(NBLK), dim3(256), 0, stream>>>(
                out, tf, ws, phase ? b1p : b1q, phase ? b2p : b2q,
                phase, tcur, dtmax);
            if (phase) tp += dtmax; else tq += dtmax;
        }
    }
}